// Round 9
// baseline (91.670 us; speedup 1.0000x reference)
//
#include <hip/hip_runtime.h>
#include <math.h>

// FrequencyMaskingLoss — psychoacoustic masking loss (forward only, scalar out).
// Pipeline (3 launches):
//   [K0] <<<3,256>>>  constant tables (f64 math), block-specialized
//   [K1] <<<nf,256>>> STFT — round-4 PROVEN register/shuffle FFT (2 elems/
//        thread, 4 barriers). Also zeroes the ticket (visible to K3 via the
//        kernel-boundary release).
//   [K3] <<<nf,256>>> fused global-max + threshold + loss partial (round-4
//        verbatim per-frame math) + FOLDED FINALIZATION: each block publishes
//        floss[t] via atomicExch (device-coherent), orders it before a ticket
//        atomicAdd via an opaque asm data-dependency (one vmcnt wait, NOT a
//        threadfence cache-flush — round-1's mistake), and the block drawing
//        ticket nf-1 re-reads all floss via atomicAdd(p,0.0f) RMW-loads in
//        k4's EXACT reduction order -> bitwise-identical out[0].
// WINDOW=512, HOP=128, F=257, n_frames=(L-512)/128+1 (=1247 for L=160000).

#define FBINS 257

// table layout inside ws (floats): barkf[257] | athdb[257] | athp[257] |
//                                  hann[512] | twr[256] | twi[256]
#define TAB_BARK  0
#define TAB_ATHDB 257
#define TAB_ATHP  514
#define TAB_HANN  771
#define TAB_TWR   1283
#define TAB_TWI   1539
#define TAB_FLOATS 2048   // padded

// ---------------------------------------------------------------- kernel 0
// 3 blocks on 3 CUs: block0 = freq tables, block1 = hann, block2 = twiddles.
__global__ __launch_bounds__(256) void k0_init(float* __restrict__ tab)
{
    const int tid = threadIdx.x;
    const double TWO_PI = 6.283185307179586476925286766559;
    if (blockIdx.x == 0) {
        for (int f = tid; f < FBINS; f += 256) {
            double freq = 31.25 * (double)f;            // SR/2/256 * f, exact
            double q    = freq / 7500.0;
            tab[TAB_BARK + f] = (float)(13.0 * atan(0.00076 * freq) + 3.5 * atan(q * q));
            if (f == 0) {
                tab[TAB_ATHDB] = -INFINITY;
                tab[TAB_ATHP]  = 0.0f;
            } else {
                double fk = freq * 0.001;
                double ad = 3.64 * pow(fk, -0.8)
                          - 6.5 * exp(-0.6 * (fk - 3.3) * (fk - 3.3))
                          + 0.001 * fk * fk * fk * fk - 12.0;
                float av = (float)ad;
                tab[TAB_ATHDB + f] = av;
                tab[TAB_ATHP  + f] = exp10f(av / 10.0f);
            }
        }
    } else if (blockIdx.x == 1) {
        for (int n = tid; n < 512; n += 256) {
            double cw = cos((TWO_PI * (double)n) / 512.0);
            tab[TAB_HANN + n] = (float)(0.5 * (1.0 - cw));
        }
    } else {
        for (int j = tid; j < 256; j += 256) {
            double s, c;
            sincos(-(TWO_PI / 512.0) * (double)j, &s, &c);
            tab[TAB_TWR + j] = (float)c;
            tab[TAB_TWI + j] = (float)s;
        }
    }
}

// ---------------------------------------------------------------- kernel 1
// (round-4 verbatim) One frame per block; z = hann*ref + i*hann*delta ->
// one 512-pt complex FFT. Register-resident radix-2 DIT, 2 elems/thread.
// Block 0 additionally zeroes the ticket for K3.
__global__ __launch_bounds__(256) void k1_stft(
    const float* __restrict__ xadv, const float* __restrict__ xref,
    const float* __restrict__ tab,
    float* __restrict__ psd_db, float* __restrict__ pd, float* __restrict__ fmaxs,
    unsigned int* __restrict__ ticket)
{
    __shared__ float2 tw2[256];
    __shared__ float2 bufA[256], bufB[256];
    __shared__ float2 zf[512];
    __shared__ float wmax[4];
    const int t = blockIdx.x, tid = threadIdx.x;

    if (t == 0 && tid == 0) ticket[0] = 0u;   // kernel-boundary release -> K3 sees it

    tw2[tid] = make_float2(tab[TAB_TWR + tid], tab[TAB_TWI + tid]);

    const int base_idx = t * 128;
    const int n0 = (int)(__brev((unsigned)tid) >> 24);
    const int n1 = n0 + 256;
    float w0 = tab[TAB_HANN + n0], w1 = tab[TAB_HANN + n1];
    float r0 = xref[base_idx + n0], r1 = xref[base_idx + n1];
    float a0 = xadv[base_idx + n0], a1 = xadv[base_idx + n1];
    float2 E0 = make_float2(w0 * r0, w0 * (a0 - r0));
    float2 E1 = make_float2(w1 * r1, w1 * (a1 - r1));
    __syncthreads();

    #pragma unroll
    for (int s = 1; s <= 7; ++s) {
        const int half  = 1 << (s - 1);
        const int tstep = 512 >> s;
        float2 w = tw2[(tid & (half - 1)) * tstep];
        float vr = E1.x * w.x - E1.y * w.y;
        float vi = E1.x * w.y + E1.y * w.x;
        float ur = E0.x, ui = E0.y;
        E0 = make_float2(ur + vr, ui + vi);
        E1 = make_float2(ur - vr, ui - vi);
        if (s <= 6) {
            const int d = 1 << (s - 1);
            int b = (tid >> (s - 1)) & 1;
            float2 keep = b ? E1 : E0;
            float2 send = b ? E0 : E1;
            float2 recv;
            recv.x = __shfl_xor(send.x, d);
            recv.y = __shfl_xor(send.y, d);
            E0 = b ? recv : keep;
            E1 = b ? keep : recv;
        }
    }
    {
        int b = (tid >> 6) & 1;
        float2 keep = b ? E1 : E0;
        bufA[tid] = b ? E0 : E1;
        __syncthreads();
        float2 recv = bufA[tid ^ 64];
        E0 = b ? recv : keep;
        E1 = b ? keep : recv;
    }
    {
        float2 w = tw2[(tid & 127) * 2];
        float vr = E1.x * w.x - E1.y * w.y;
        float vi = E1.x * w.y + E1.y * w.x;
        float ur = E0.x, ui = E0.y;
        E0 = make_float2(ur + vr, ui + vi);
        E1 = make_float2(ur - vr, ui - vi);
    }
    {
        int b = (tid >> 7) & 1;
        float2 keep = b ? E1 : E0;
        bufB[tid] = b ? E0 : E1;
        __syncthreads();
        float2 recv = bufB[tid ^ 128];
        E0 = b ? recv : keep;
        E1 = b ? keep : recv;
    }
    {
        float2 w = tw2[tid];
        float vr = E1.x * w.x - E1.y * w.y;
        float vi = E1.x * w.y + E1.y * w.x;
        float ur = E0.x, ui = E0.y;
        E0 = make_float2(ur + vr, ui + vi);
        E1 = make_float2(ur - vr, ui - vi);
    }
    zf[tid]       = E0;
    zf[tid + 256] = E1;
    __syncthreads();

    const float S2 = 1.0172526041666667e-05f;   // (sqrt(8/3)/512)^2
    float lmax = -1e30f;
    for (int k = tid; k <= 256; k += 256) {
        int nk = (512 - k) & 511;
        float2 zk = zf[k];
        float2 zn = zf[nk];
        float ar = 0.5f * (zk.x + zn.x), ai = 0.5f * (zk.y - zn.y);   // ref spectrum
        float br = 0.5f * (zk.y + zn.y), bi = 0.5f * (zn.x - zk.x);   // delta spectrum
        float prefp = S2 * (ar * ar + ai * ai);
        float pdb   = fmaxf(10.0f * log10f(prefp), -200.0f);
        psd_db[t * FBINS + k] = pdb;
        pd[t * FBINS + k]     = S2 * (br * br + bi * bi);
        lmax = fmaxf(lmax, pdb);
    }
    for (int off = 32; off > 0; off >>= 1) lmax = fmaxf(lmax, __shfl_down(lmax, off));
    if ((tid & 63) == 0) wmax[tid >> 6] = lmax;
    __syncthreads();
    if (tid == 0)
        fmaxs[t] = fmaxf(fmaxf(wmax[0], wmax[1]), fmaxf(wmax[2], wmax[3]));
}

// ---------------------------------------------------------------- kernel 3
// Round-4 per-frame math verbatim; adds the folded finalization (see header).
__global__ __launch_bounds__(256) void k3_threshold(
    const float* __restrict__ tab,
    const float* __restrict__ psd_db, const float* __restrict__ pd,
    const float* __restrict__ fmaxs, int nf, float* __restrict__ floss,
    unsigned int* __restrict__ ticket, float* __restrict__ out)
{
    __shared__ float barkf[FBINS], athp_s[FBINS];
    __shared__ float p_s[FBINS], pw_s[FBINS];
    __shared__ float mc_s[128], shift_s[128], barkm_s[128], ups_s[128];
    __shared__ int   bin_s[128], keep_s[128];
    __shared__ float2 pmk[132];
    __shared__ int   wcnt[4];
    __shared__ float red[4];
    __shared__ float sm[4];
    __shared__ int   lastflag;

    const int t = blockIdx.x, tid = threadIdx.x;
    const int lane = tid & 63, wid = tid >> 6;

    const float pdb_a = psd_db[t * FBINS + tid];
    const float pdb_b = psd_db[t * FBINS + 256];

    for (int f = tid; f < FBINS; f += 256) {
        barkf[f]  = tab[TAB_BARK + f];
        athp_s[f] = tab[TAB_ATHP + f];
    }
    float v = -1e30f;
    for (int i = tid; i < nf; i += 256) v = fmaxf(v, fmaxs[i]);
    for (int off = 32; off > 0; off >>= 1) v = fmaxf(v, __shfl_down(v, off));
    if (lane == 0) sm[wid] = v;
    __syncthreads();
    const float pmax   = fmaxf(fmaxf(sm[0], sm[1]), fmaxf(sm[2], sm[3]));
    const float shift0 = 96.0f - pmax;

    {
        float pv = shift0 + pdb_a;
        p_s[tid]  = pv;
        pw_s[tid] = exp10f(pv / 10.0f);
        if (tid == 0) {
            float pv2 = shift0 + pdb_b;
            p_s[256]  = pv2;
            pw_s[256] = exp10f(pv2 / 10.0f);
        }
    }
    __syncthreads();

    float m = -1e30f;
    int   pred = 0;
    if (tid >= 1 && tid <= 255) {
        float pc = p_s[tid];
        if (pc > p_s[tid - 1] && pc > p_s[tid + 1]) {
            m = 10.0f * log10f((pw_s[tid] + pw_s[tid - 1]) + pw_s[tid + 1]);
            if (m > tab[TAB_ATHDB + tid]) pred = 1;
        }
    }
    unsigned long long bal = __ballot(pred);
    if (lane == 0) wcnt[wid] = __popcll(bal);
    __syncthreads();
    int base = 0;
    for (int w = 0; w < wid; ++w) base += wcnt[w];
    const int n_total = wcnt[0] + wcnt[1] + wcnt[2] + wcnt[3];
    if (pred) {
        int pos = base + __popcll(bal & ((1ull << lane) - 1));
        bin_s[pos] = tid; mc_s[pos] = m; keep_s[pos] = 1;
    }
    __syncthreads();

    if (tid <= n_total && tid < 130) {
        pmk[tid] = (tid < n_total) ? make_float2(barkf[tid], mc_s[tid])
                                   : make_float2(1.0e30f, -1.0e30f);
    }
    __syncthreads();

    if (tid == 0 && n_total > 1) {
        int   i_prev = 0;
        float bp = pmk[0].x, mp = pmk[0].y;
        float2 c = pmk[1];
        for (int i = 1; i < n_total; ++i) {
            float2 nx = pmk[i + 1];
            bool close        = (c.x - bp) < 0.5f;
            bool prev_smaller = mp < c.y;
            if (close) {
                keep_s[prev_smaller ? i_prev : i] = 0;
                if (prev_smaller) {
                    ++i_prev;
                    if (i_prev == i) { bp = c.x; mp = c.y; }
                    else { float2 p = pmk[i_prev]; bp = p.x; mp = p.y; }
                }
            } else {
                i_prev = i; bp = c.x; mp = c.y;
            }
            c = nx;
        }
    }
    __syncthreads();

    int pred2 = (tid < n_total) && keep_s[tid];
    unsigned long long bal2 = __ballot(pred2);
    if (lane == 0) wcnt[wid] = __popcll(bal2);
    __syncthreads();
    int base2 = 0;
    for (int w = 0; w < wid; ++w) base2 += wcnt[w];
    const int nk = wcnt[0] + wcnt[1] + wcnt[2] + wcnt[3];
    if (pred2) {
        int pos = base2 + __popcll(bal2 & ((1ull << lane) - 1));
        int   fb = bin_s[tid];
        float mc = mc_s[tid];
        shift_s[pos] = mc + (-6.025f - 0.275f * barkf[fb]);
        barkm_s[pos] = barkf[fb];
        ups_s[pos]   = -27.0f + 0.37f * fmaxf(mc - 40.0f, 0.0f);
    }
    __syncthreads();

    const float C = 3981071705.534973f / exp10f(pmax / 10.0f);  // 10^9.6/10^(pmax/10)
    float lsum = 0.0f;
    for (int f = tid; f < FBINS; f += 256) {
        float bf  = barkf[f];
        float acc = 0.0f;
        for (int k = 0; k < nk; ++k) {
            float dz    = bf - barkm_s[k];
            float slope = (dz > 0.0f) ? ups_s[k] : 27.0f;
            float tdb   = shift_s[k] + slope * dz;
            acc += exp10f(tdb / 10.0f);
        }
        float thrpow = acc + athp_s[f];
        float pds    = C * pd[t * FBINS + f];
        lsum += fmaxf(pds - thrpow, 0.0f);
    }
    for (int off = 32; off > 0; off >>= 1) lsum += __shfl_down(lsum, off);
    if ((tid & 63) == 0) red[tid >> 6] = lsum;
    __syncthreads();

    // ---- folded finalization (replaces K4) ----
    if (tid == 0) {
        float total = (red[0] + red[1]) + (red[2] + red[3]);
        // publish at the device coherence point (plain stores are NOT
        // cross-XCD visible within a dispatch)
        float old = atomicExch(&floss[t], total);
        // opaque dep: forces vmcnt wait on the exch BEFORE the ticket RMW
        // issues (cheap per-thread ordering; NOT a threadfence cache flush)
        unsigned int z;
        asm volatile("v_mov_b32 %0, 0" : "=v"(z) : "v"(old));
        unsigned int tk = atomicAdd(ticket, 1u + z);   // z == 0, opaque to compiler
        lastflag = (tk == (unsigned int)(nf - 1)) ? 1 : 0;
    }
    __syncthreads();

    if (lastflag) {
        // k4's EXACT reduction order, with coherent RMW-loads
        float s = 0.0f;
        for (int i = tid; i < nf; i += 256) s += atomicAdd(&floss[i], 0.0f);
        for (int off = 32; off > 0; off >>= 1) s += __shfl_down(s, off);
        if ((tid & 63) == 0) red[tid >> 6] = s;
        __syncthreads();
        if (tid == 0) {
            float total = (red[0] + red[1]) + (red[2] + red[3]);
            out[0] = 1e-6f * (total / (float)(nf * FBINS));
        }
    }
}

// ---------------------------------------------------------------- launch
extern "C" void kernel_launch(void* const* d_in, const int* in_sizes, int n_in,
                              void* d_out, int out_size, void* d_ws, size_t ws_size,
                              hipStream_t stream)
{
    const float* x_adv = (const float*)d_in[0];
    const float* x_ref = (const float*)d_in[1];
    float*       out   = (float*)d_out;

    const int L  = in_sizes[0];
    const int nf = (L - 512) / 128 + 1;           // 1247 for L=160000

    // workspace layout (floats)
    float* ws      = (float*)d_ws;
    float* tab     = ws;                                   // TAB_FLOATS
    float* psd_db  = ws + TAB_FLOATS;                      // nf*257
    float* pd      = psd_db + (size_t)nf * FBINS;          // nf*257
    float* fmaxs   = pd + (size_t)nf * FBINS;              // nf
    float* floss   = fmaxs + nf;                           // nf
    unsigned int* ticket = (unsigned int*)(floss + nf);    // 1

    k0_init     <<<3,  256, 0, stream>>>(tab);
    k1_stft     <<<nf, 256, 0, stream>>>(x_adv, x_ref, tab, psd_db, pd, fmaxs, ticket);
    k3_threshold<<<nf, 256, 0, stream>>>(tab, psd_db, pd, fmaxs, nf, floss, ticket, out);
}

// Round 10
// 84.368 us; speedup vs baseline: 1.0865x; 1.0865x over previous
//
#include <hip/hip_runtime.h>
#include <math.h>

// FrequencyMaskingLoss — psychoacoustic masking loss (forward only, scalar out).
// Pipeline (3 launches, NO cross-block coherence tricks — r5/r9 measured those
// as regressions):
//   [K1] <<<nf,256>>> STFT — round-4 PROVEN register/shuffle FFT (2 elems/
//        thread), with k0 FOLDED IN: hann + twiddle are per-thread f64
//        recomputes (2 cos + 1 sincos, hidden under the input loads; bitwise
//        == old k0 tables), and block 0 writes bark/ATH tables to global tab
//        for K3 (k1->k3 kernel boundary = visibility).
//   [K3] <<<nf,256>>> fused global-max + threshold + loss partial (round-4
//        verbatim: redundant per-block fmaxs reduce in k2's exact order ->
//        bitwise-same pmax; software-pipelined serial i_prev scan).
//   [K4] <<<1,256>>>  mean -> out[0] (round-4 verbatim).
// WINDOW=512, HOP=128, F=257, n_frames=(L-512)/128+1 (=1247 for L=160000).
//
// Lessons encoded: __shfl == ds_bpermute (same LDS hw) so shfl-heavy FFTs
// regress (r6); grid.sync / same-line atomic tickets cost more than a launch
// (r5/r9); 2-frames-per-block k3 neutral (r7).

#define FBINS 257

// table layout inside ws (floats): barkf[257] | athdb[257] | athp[257]
#define TAB_BARK  0
#define TAB_ATHDB 257
#define TAB_ATHP  514
#define TAB_FLOATS 1024   // padded

// ---------------------------------------------------------------- kernel 1
// One frame per block; z = hann*ref + i*hann*delta -> one 512-pt complex FFT.
// Register-resident radix-2 DIT, 2 elems/thread. Tables inlined (see header).
__global__ __launch_bounds__(256) void k1_stft(
    const float* __restrict__ xadv, const float* __restrict__ xref,
    float* __restrict__ tab,
    float* __restrict__ psd_db, float* __restrict__ pd, float* __restrict__ fmaxs)
{
    __shared__ float2 tw2[256];
    __shared__ float2 bufA[256], bufB[256];
    __shared__ float2 zf[512];
    __shared__ float wmax[4];
    const int t = blockIdx.x, tid = threadIdx.x;
    const double TWO_PI = 6.283185307179586476925286766559;

    // twiddle: identical f64 expression to the old k0 -> bitwise-same table
    {
        double s, c;
        sincos(-(TWO_PI / 512.0) * (double)tid, &s, &c);
        tw2[tid] = make_float2((float)c, (float)s);
    }

    // block 0 publishes the frequency-domain tables for K3 (k0-block0 verbatim)
    if (t == 0) {
        for (int f = tid; f < FBINS; f += 256) {
            double freq = 31.25 * (double)f;            // SR/2/256 * f, exact
            double q    = freq / 7500.0;
            tab[TAB_BARK + f] = (float)(13.0 * atan(0.00076 * freq) + 3.5 * atan(q * q));
            if (f == 0) {
                tab[TAB_ATHDB] = -INFINITY;
                tab[TAB_ATHP]  = 0.0f;
            } else {
                double fk = freq * 0.001;
                double ad = 3.64 * pow(fk, -0.8)
                          - 6.5 * exp(-0.6 * (fk - 3.3) * (fk - 3.3))
                          + 0.001 * fk * fk * fk * fk - 12.0;
                float av = (float)ad;
                tab[TAB_ATHDB + f] = av;
                tab[TAB_ATHP  + f] = exp10f(av / 10.0f);
            }
        }
    }

    // bit-reversed input load; hann weights recomputed per-thread in f64
    // (identical expression to old k0 -> bitwise-same float weights)
    const int base_idx = t * 128;
    const int n0 = (int)(__brev((unsigned)tid) >> 24);
    const int n1 = n0 + 256;
    float r0 = xref[base_idx + n0], r1 = xref[base_idx + n1];
    float a0 = xadv[base_idx + n0], a1 = xadv[base_idx + n1];
    float w0 = (float)(0.5 * (1.0 - cos((TWO_PI * (double)n0) / 512.0)));
    float w1 = (float)(0.5 * (1.0 - cos((TWO_PI * (double)n1) / 512.0)));
    float2 E0 = make_float2(w0 * r0, w0 * (a0 - r0));
    float2 E1 = make_float2(w1 * r1, w1 * (a1 - r1));
    __syncthreads();   // tw2 ready

    #pragma unroll
    for (int s = 1; s <= 7; ++s) {
        const int half  = 1 << (s - 1);
        const int tstep = 512 >> s;
        float2 w = tw2[(tid & (half - 1)) * tstep];
        float vr = E1.x * w.x - E1.y * w.y;
        float vi = E1.x * w.y + E1.y * w.x;
        float ur = E0.x, ui = E0.y;
        E0 = make_float2(ur + vr, ui + vi);
        E1 = make_float2(ur - vr, ui - vi);
        if (s <= 6) {
            const int d = 1 << (s - 1);
            int b = (tid >> (s - 1)) & 1;
            float2 keep = b ? E1 : E0;
            float2 send = b ? E0 : E1;
            float2 recv;
            recv.x = __shfl_xor(send.x, d);
            recv.y = __shfl_xor(send.y, d);
            E0 = b ? recv : keep;
            E1 = b ? keep : recv;
        }
    }
    {   // cross-wave re-pair (distance 64) via LDS
        int b = (tid >> 6) & 1;
        float2 keep = b ? E1 : E0;
        bufA[tid] = b ? E0 : E1;
        __syncthreads();
        float2 recv = bufA[tid ^ 64];
        E0 = b ? recv : keep;
        E1 = b ? keep : recv;
    }
    {   // stage 8
        float2 w = tw2[(tid & 127) * 2];
        float vr = E1.x * w.x - E1.y * w.y;
        float vi = E1.x * w.y + E1.y * w.x;
        float ur = E0.x, ui = E0.y;
        E0 = make_float2(ur + vr, ui + vi);
        E1 = make_float2(ur - vr, ui - vi);
    }
    {   // cross-wave re-pair (distance 128) via LDS
        int b = (tid >> 7) & 1;
        float2 keep = b ? E1 : E0;
        bufB[tid] = b ? E0 : E1;
        __syncthreads();
        float2 recv = bufB[tid ^ 128];
        E0 = b ? recv : keep;
        E1 = b ? keep : recv;
    }
    {   // stage 9
        float2 w = tw2[tid];
        float vr = E1.x * w.x - E1.y * w.y;
        float vi = E1.x * w.y + E1.y * w.x;
        float ur = E0.x, ui = E0.y;
        E0 = make_float2(ur + vr, ui + vi);
        E1 = make_float2(ur - vr, ui - vi);
    }
    zf[tid]       = E0;
    zf[tid + 256] = E1;
    __syncthreads();

    const float S2 = 1.0172526041666667e-05f;   // (sqrt(8/3)/512)^2
    float lmax = -1e30f;
    for (int k = tid; k <= 256; k += 256) {
        int nk = (512 - k) & 511;
        float2 zk = zf[k];
        float2 zn = zf[nk];
        float ar = 0.5f * (zk.x + zn.x), ai = 0.5f * (zk.y - zn.y);   // ref spectrum
        float br = 0.5f * (zk.y + zn.y), bi = 0.5f * (zn.x - zk.x);   // delta spectrum
        float prefp = S2 * (ar * ar + ai * ai);
        float pdb   = fmaxf(10.0f * log10f(prefp), -200.0f);
        psd_db[t * FBINS + k] = pdb;
        pd[t * FBINS + k]     = S2 * (br * br + bi * bi);
        lmax = fmaxf(lmax, pdb);
    }
    for (int off = 32; off > 0; off >>= 1) lmax = fmaxf(lmax, __shfl_down(lmax, off));
    if ((tid & 63) == 0) wmax[tid >> 6] = lmax;
    __syncthreads();
    if (tid == 0)
        fmaxs[t] = fmaxf(fmaxf(wmax[0], wmax[1]), fmaxf(wmax[2], wmax[3]));
}

// ---------------------------------------------------------------- kernel 3
// (round-4 verbatim) fused global-max + threshold + loss partial.
__global__ __launch_bounds__(256) void k3_threshold(
    const float* __restrict__ tab,
    const float* __restrict__ psd_db, const float* __restrict__ pd,
    const float* __restrict__ fmaxs, int nf, float* __restrict__ floss)
{
    __shared__ float barkf[FBINS], athp_s[FBINS];
    __shared__ float p_s[FBINS], pw_s[FBINS];
    __shared__ float mc_s[128], shift_s[128], barkm_s[128], ups_s[128];
    __shared__ int   bin_s[128], keep_s[128];
    __shared__ float2 pmk[132];
    __shared__ int   wcnt[4];
    __shared__ float red[4];
    __shared__ float sm[4];

    const int t = blockIdx.x, tid = threadIdx.x;
    const int lane = tid & 63, wid = tid >> 6;

    const float pdb_a = psd_db[t * FBINS + tid];
    const float pdb_b = psd_db[t * FBINS + 256];

    for (int f = tid; f < FBINS; f += 256) {
        barkf[f]  = tab[TAB_BARK + f];
        athp_s[f] = tab[TAB_ATHP + f];
    }
    float v = -1e30f;
    for (int i = tid; i < nf; i += 256) v = fmaxf(v, fmaxs[i]);
    for (int off = 32; off > 0; off >>= 1) v = fmaxf(v, __shfl_down(v, off));
    if (lane == 0) sm[wid] = v;
    __syncthreads();
    const float pmax   = fmaxf(fmaxf(sm[0], sm[1]), fmaxf(sm[2], sm[3]));
    const float shift0 = 96.0f - pmax;

    {
        float pv = shift0 + pdb_a;
        p_s[tid]  = pv;
        pw_s[tid] = exp10f(pv / 10.0f);
        if (tid == 0) {
            float pv2 = shift0 + pdb_b;
            p_s[256]  = pv2;
            pw_s[256] = exp10f(pv2 / 10.0f);
        }
    }
    __syncthreads();

    float m = -1e30f;
    int   pred = 0;
    if (tid >= 1 && tid <= 255) {
        float pc = p_s[tid];
        if (pc > p_s[tid - 1] && pc > p_s[tid + 1]) {
            m = 10.0f * log10f((pw_s[tid] + pw_s[tid - 1]) + pw_s[tid + 1]);
            if (m > tab[TAB_ATHDB + tid]) pred = 1;
        }
    }
    unsigned long long bal = __ballot(pred);
    if (lane == 0) wcnt[wid] = __popcll(bal);
    __syncthreads();
    int base = 0;
    for (int w = 0; w < wid; ++w) base += wcnt[w];
    const int n_total = wcnt[0] + wcnt[1] + wcnt[2] + wcnt[3];
    if (pred) {
        int pos = base + __popcll(bal & ((1ull << lane) - 1));
        bin_s[pos] = tid; mc_s[pos] = m; keep_s[pos] = 1;
    }
    __syncthreads();

    if (tid <= n_total && tid < 130) {
        pmk[tid] = (tid < n_total) ? make_float2(barkf[tid], mc_s[tid])
                                   : make_float2(1.0e30f, -1.0e30f);
    }
    __syncthreads();

    if (tid == 0 && n_total > 1) {
        int   i_prev = 0;
        float bp = pmk[0].x, mp = pmk[0].y;
        float2 c = pmk[1];
        for (int i = 1; i < n_total; ++i) {
            float2 nx = pmk[i + 1];
            bool close        = (c.x - bp) < 0.5f;
            bool prev_smaller = mp < c.y;
            if (close) {
                keep_s[prev_smaller ? i_prev : i] = 0;
                if (prev_smaller) {
                    ++i_prev;
                    if (i_prev == i) { bp = c.x; mp = c.y; }
                    else { float2 p = pmk[i_prev]; bp = p.x; mp = p.y; }
                }
            } else {
                i_prev = i; bp = c.x; mp = c.y;
            }
            c = nx;
        }
    }
    __syncthreads();

    int pred2 = (tid < n_total) && keep_s[tid];
    unsigned long long bal2 = __ballot(pred2);
    if (lane == 0) wcnt[wid] = __popcll(bal2);
    __syncthreads();
    int base2 = 0;
    for (int w = 0; w < wid; ++w) base2 += wcnt[w];
    const int nk = wcnt[0] + wcnt[1] + wcnt[2] + wcnt[3];
    if (pred2) {
        int pos = base2 + __popcll(bal2 & ((1ull << lane) - 1));
        int   fb = bin_s[tid];
        float mc = mc_s[tid];
        shift_s[pos] = mc + (-6.025f - 0.275f * barkf[fb]);
        barkm_s[pos] = barkf[fb];
        ups_s[pos]   = -27.0f + 0.37f * fmaxf(mc - 40.0f, 0.0f);
    }
    __syncthreads();

    const float C = 3981071705.534973f / exp10f(pmax / 10.0f);  // 10^9.6/10^(pmax/10)
    float lsum = 0.0f;
    for (int f = tid; f < FBINS; f += 256) {
        float bf  = barkf[f];
        float acc = 0.0f;
        for (int k = 0; k < nk; ++k) {
            float dz    = bf - barkm_s[k];
            float slope = (dz > 0.0f) ? ups_s[k] : 27.0f;
            float tdb   = shift_s[k] + slope * dz;
            acc += exp10f(tdb / 10.0f);
        }
        float thrpow = acc + athp_s[f];
        float pds    = C * pd[t * FBINS + f];
        lsum += fmaxf(pds - thrpow, 0.0f);
    }
    for (int off = 32; off > 0; off >>= 1) lsum += __shfl_down(lsum, off);
    if ((tid & 63) == 0) red[tid >> 6] = lsum;
    __syncthreads();
    if (tid == 0) floss[t] = (red[0] + red[1]) + (red[2] + red[3]);
}

// ---------------------------------------------------------------- kernel 4
__global__ __launch_bounds__(256) void k4_final(
    const float* __restrict__ floss, int nf, float* __restrict__ out)
{
    __shared__ float red[4];
    float s = 0.0f;
    for (int i = threadIdx.x; i < nf; i += 256) s += floss[i];
    for (int off = 32; off > 0; off >>= 1) s += __shfl_down(s, off);
    if ((threadIdx.x & 63) == 0) red[threadIdx.x >> 6] = s;
    __syncthreads();
    if (threadIdx.x == 0) {
        float total = (red[0] + red[1]) + (red[2] + red[3]);
        out[0] = 1e-6f * (total / (float)(nf * FBINS));
    }
}

// ---------------------------------------------------------------- launch
extern "C" void kernel_launch(void* const* d_in, const int* in_sizes, int n_in,
                              void* d_out, int out_size, void* d_ws, size_t ws_size,
                              hipStream_t stream)
{
    const float* x_adv = (const float*)d_in[0];
    const float* x_ref = (const float*)d_in[1];
    float*       out   = (float*)d_out;

    const int L  = in_sizes[0];
    const int nf = (L - 512) / 128 + 1;           // 1247 for L=160000

    // workspace layout (floats)
    float* ws      = (float*)d_ws;
    float* tab     = ws;                                   // TAB_FLOATS
    float* psd_db  = ws + TAB_FLOATS;                      // nf*257
    float* pd      = psd_db + (size_t)nf * FBINS;          // nf*257
    float* fmaxs   = pd + (size_t)nf * FBINS;              // nf
    float* floss   = fmaxs + nf;                           // nf

    k1_stft     <<<nf, 256, 0, stream>>>(x_adv, x_ref, tab, psd_db, pd, fmaxs);
    k3_threshold<<<nf, 256, 0, stream>>>(tab, psd_db, pd, fmaxs, nf, floss);
    k4_final    <<<1,  256, 0, stream>>>(floss, nf, out);
}